// Round 1
// baseline (24132.475 us; speedup 1.0000x reference)
//
#include <hip/hip_runtime.h>
#include <hip/hip_bf16.h>

// LSTM decoder: 2 layers, B=128, S=512, I=H=768.
// Persistent cooperative kernel, layer-skewed pipeline, bf16 MFMA.

#define S_LEN 512
#define BATCH 128
#define HID   768
#define KDIM  1536          // I + H (concatenated GEMM K)
#define NCOLS 3072          // 4*H gate columns per layer
#define UPW   6             // hidden units per WG (768/128)
#define CPW   24            // gate cols per WG (4*UPW)
#define KSTR  1544          // LDS weight row stride in bf16 elems (1536 + 8 pad, keeps 16B align)
#define NWG   256

typedef unsigned short u16;
typedef unsigned int   u32;
typedef __attribute__((ext_vector_type(8))) __bf16 bf16x8;
typedef __attribute__((ext_vector_type(4))) float  f32x4;

// ---- ws layout (bytes) ----
static constexpr size_t XBF_OFF = 0;                                   // [S][B][I] bf16
static constexpr size_t XBF_BYTES = (size_t)S_LEN * BATCH * HID * 2;   // 100,663,296
static constexpr size_t W0_OFF  = XBF_OFF + XBF_BYTES;                 // [3072][1536] bf16 (permuted rows)
static constexpr size_t WP_BYTES = (size_t)NCOLS * KDIM * 2;           // 9,437,184
static constexpr size_t W1_OFF  = W0_OFF + WP_BYTES;
static constexpr size_t B0_OFF  = W1_OFF + WP_BYTES;                   // [3072] f32 (permuted, b_ih+b_hh)
static constexpr size_t B1_OFF  = B0_OFF + NCOLS * 4;
static constexpr size_t R0_OFF  = B1_OFF + NCOLS * 4;                  // [2][B][H] bf16 ring (layer0 h)
static constexpr size_t RING_BYTES = 2ull * BATCH * HID * 2;
static constexpr size_t R1_OFF  = R0_OFF + RING_BYTES;                 // [2][B][H] bf16 ring (layer1 h)
static constexpr size_t BAR_OFF = R1_OFF + RING_BYTES;
static constexpr size_t WS_NEED = BAR_OFF + 256;

// dynamic LDS layout (bytes)
static constexpr int WT_B  = 32 * KSTR * 2;          // 98,816 weight slice (24 real + 8 zero rows)
static constexpr int GS_B  = 4 * BATCH * 25 * 4;     // 51,200 per-wave partial gates [4][128][25]
static constexpr int CB_B  = UPW * BATCH * 4;        //  3,072 c-state [6][128]
static constexpr int BS_B  = 32 * 4;                 //    128 bias slice (24 used)
static constexpr int HB_B  = BATCH * UPW * 2;        //  1,536 h staging [128][6]
static constexpr int DYN_LDS = WT_B + GS_B + CB_B + BS_B + HB_B;   // 154,752 <= 160K

__device__ __forceinline__ u16 f2bf(float f) {
  u32 u = __float_as_uint(f);
  u = (u + 0x7fffu + ((u >> 16) & 1u)) >> 16;
  return (u16)u;
}
__device__ __forceinline__ float sigm(float x)  { return 1.0f / (1.0f + __expf(-x)); }
__device__ __forceinline__ float tanhf_(float x){ return 1.0f - 2.0f / (1.0f + __expf(2.0f * x)); }

// ---------- prep kernels ----------
__global__ void prep_w(const float* __restrict__ Wih0, const float* __restrict__ Whh0,
                       const float* __restrict__ bih0, const float* __restrict__ bhh0,
                       const float* __restrict__ Wih1, const float* __restrict__ Whh1,
                       const float* __restrict__ bih1, const float* __restrict__ bhh1,
                       u16* __restrict__ W0p, u16* __restrict__ W1p,
                       float* __restrict__ b0p, float* __restrict__ b1p) {
  int p = blockIdx.x;            // permuted row 0..3071:  p = u*4 + gate
  int u = p >> 2, g = p & 3;
  int n = g * HID + u;           // original gate row (i,f,g,o blocks of 768)
  const float* s0i = Wih0 + (size_t)n * HID;
  const float* s0h = Whh0 + (size_t)n * HID;
  const float* s1i = Wih1 + (size_t)n * HID;
  const float* s1h = Whh1 + (size_t)n * HID;
  u16* d0 = W0p + (size_t)p * KDIM;
  u16* d1 = W1p + (size_t)p * KDIM;
  for (int k = threadIdx.x; k < HID; k += blockDim.x) {
    d0[k]       = f2bf(s0i[k]);
    d0[k + HID] = f2bf(s0h[k]);
    d1[k]       = f2bf(s1i[k]);
    d1[k + HID] = f2bf(s1h[k]);
  }
  if (threadIdx.x == 0) { b0p[p] = bih0[n] + bhh0[n]; b1p[p] = bih1[n] + bhh1[n]; }
}

__global__ void prep_x(const float* __restrict__ x, u16* __restrict__ xbf) {
  // x [B][S][I] f32  ->  xbf [S][B][I] bf16
  const long long total4 = (long long)BATCH * S_LEN * HID / 4;
  long long stride = (long long)gridDim.x * blockDim.x;
  for (long long i4 = (long long)blockIdx.x * blockDim.x + threadIdx.x; i4 < total4; i4 += stride) {
    long long e = i4 * 4;
    int i = (int)(e % HID);
    long long bs = e / HID;
    int s = (int)(bs % S_LEN);
    int b = (int)(bs / S_LEN);
    float4 v = *(const float4*)(x + ((size_t)b * S_LEN + s) * HID + i);
    ushort4 o;
    o.x = f2bf(v.x); o.y = f2bf(v.y); o.z = f2bf(v.z); o.w = f2bf(v.w);
    *(ushort4*)(xbf + ((size_t)s * BATCH + b) * HID + i) = o;
  }
}

__global__ void prep_state(const float* __restrict__ h_init, u16* __restrict__ r0, u16* __restrict__ r1) {
  int i = blockIdx.x * blockDim.x + threadIdx.x;
  if (i < BATCH * HID) {
    u16 v = f2bf(h_init[i]);
    r0[BATCH * HID + i] = v;   // ring slot 1 = "step -1" state
    r1[BATCH * HID + i] = v;
  }
}

// ---------- grid barrier (agent scope; acquire/release handle cross-XCD L2) ----------
__device__ __forceinline__ void gbar(u32* bar) {
  __syncthreads();
  if (threadIdx.x == 0) {
    u32 g = __hip_atomic_load(bar + 1, __ATOMIC_ACQUIRE, __HIP_MEMORY_SCOPE_AGENT);
    u32 a = __hip_atomic_fetch_add(bar, 1u, __ATOMIC_ACQ_REL, __HIP_MEMORY_SCOPE_AGENT);
    if (a == NWG - 1) {
      __hip_atomic_store(bar, 0u, __ATOMIC_RELAXED, __HIP_MEMORY_SCOPE_AGENT);
      __hip_atomic_store(bar + 1, g + 1u, __ATOMIC_RELEASE, __HIP_MEMORY_SCOPE_AGENT);
    } else {
      while (__hip_atomic_load(bar + 1, __ATOMIC_ACQUIRE, __HIP_MEMORY_SCOPE_AGENT) == g)
        __builtin_amdgcn_s_sleep(2);
    }
  }
  __syncthreads();
}

// ---------- persistent LSTM ----------
__global__ void __launch_bounds__(256, 1)
lstm_persist(const u16* __restrict__ xbf, const u16* __restrict__ W0p, const u16* __restrict__ W1p,
             const float* __restrict__ b0p, const float* __restrict__ b1p,
             u16* __restrict__ r0, u16* __restrict__ r1,
             const float* __restrict__ c_init, float* __restrict__ out, u32* bar)
{
  extern __shared__ char lds_raw[];
  u16*   wt  = (u16*)lds_raw;                       // [32][KSTR] bf16 weights (persistent)
  float* gs  = (float*)(lds_raw + WT_B);            // [4][128][25] per-wave partial gates
  float* cb  = (float*)(lds_raw + WT_B + GS_B);     // [6][128] c-state
  float* bsl = (float*)(lds_raw + WT_B + GS_B + CB_B); // [24] bias
  u16*   hb  = (u16*)(lds_raw + WT_B + GS_B + CB_B + BS_B); // [128][6] h staging

  const int wg    = blockIdx.x;
  const int layer = wg >> 7;        // 0..127 layer0, 128..255 layer1
  const int lw    = wg & 127;
  const int tid   = threadIdx.x;
  const int lane  = tid & 63;
  const int wv    = tid >> 6;       // wave 0..3, splits K into 4x384
  const int u0    = lw * UPW;       // global hidden-unit base
  const int p0    = lw * CPW;       // permuted weight-row base

  const u16* Wp  = layer ? W1p : W0p;
  const float* bp = layer ? b1p : b0p;

  // stage weight slice (rows 0..23 real, 24..31 zero) -- once, persists all steps
  for (int f = tid; f < 32 * (KSTR / 8); f += 256) {
    int r = f / (KSTR / 8), q = f - r * (KSTR / 8);
    uint4 v = make_uint4(0u, 0u, 0u, 0u);
    if (r < CPW && q < KDIM / 8) v = *(const uint4*)(Wp + (size_t)(p0 + r) * KDIM + q * 8);
    *(uint4*)(wt + r * KSTR + q * 8) = v;
  }
  if (tid < CPW) bsl[tid] = bp[p0 + tid];
  for (int f = tid; f < UPW * BATCH; f += 256) {
    int u = f >> 7, m = f & 127;
    cb[u * BATCH + m] = c_init[(size_t)m * HID + u0 + u];   // both layers init from c_init
  }
  __syncthreads();

  const int cA = lane & 15;             // MFMA n / C-col index
  const int kq = (lane >> 4) * 8;       // quad k offset within 32-chunk

  for (int tick = 0; tick <= S_LEN; ++tick) {
    const bool active = layer ? (tick >= 1) : (tick < S_LEN);
    if (active) {
      const int s = layer ? tick - 1 : tick;
      // A = [x_t | h0_prev] (layer0)  or  [h0_t | h1_prev] (layer1), rows=batch, bf16
      const u16* A0 = layer ? r0 + (size_t)(s & 1) * (BATCH * HID)
                            : xbf + (size_t)s * (BATCH * HID);
      const u16* A1 = layer ? r1 + (size_t)((s + 1) & 1) * (BATCH * HID)
                            : r0 + (size_t)((tick + 1) & 1) * (BATCH * HID);

      const u16* Ab = (wv & 2) ? A1 : A0;
      const u16* ap = Ab + (size_t)cA * HID + (wv & 1) * 384 + kq;
      const u16* wr = wt + (size_t)cA * KSTR + wv * 384 + kq;

      f32x4 acc[8][2];
      #pragma unroll
      for (int mt = 0; mt < 8; ++mt) { acc[mt][0] = (f32x4){0.f,0.f,0.f,0.f}; acc[mt][1] = (f32x4){0.f,0.f,0.f,0.f}; }

      #pragma unroll 3
      for (int kc = 0; kc < 12; ++kc) {
        bf16x8 b0 = *(const bf16x8*)(wr + kc * 32);
        bf16x8 b1 = *(const bf16x8*)(wr + kc * 32 + 16 * KSTR);
        #pragma unroll
        for (int mt = 0; mt < 8; ++mt) {
          bf16x8 a = *(const bf16x8*)(ap + kc * 32 + (size_t)mt * 16 * HID);
          acc[mt][0] = __builtin_amdgcn_mfma_f32_16x16x32_bf16(a, b0, acc[mt][0], 0, 0, 0);
          acc[mt][1] = __builtin_amdgcn_mfma_f32_16x16x32_bf16(a, b1, acc[mt][1], 0, 0, 0);
        }
      }

      // write per-wave partial gates to LDS  (C/D: col=lane&15, row=quad*4+reg)
      float* gsp = gs + wv * (BATCH * 25);
      const int rq = (lane >> 4) * 4;
      #pragma unroll
      for (int mt = 0; mt < 8; ++mt) {
        #pragma unroll
        for (int r = 0; r < 4; ++r) {
          gsp[(mt * 16 + rq + r) * 25 + cA] = acc[mt][0][r];
          if (cA < 8) gsp[(mt * 16 + rq + r) * 25 + 16 + cA] = acc[mt][1][r];
        }
      }
      __syncthreads();

      u16* hw = layer ? r1 + (size_t)(s & 1) * (BATCH * HID)
                      : r0 + (size_t)(tick & 1) * (BATCH * HID);

      // elementwise LSTM cell for this WG's 6 units x 128 batches
      #pragma unroll
      for (int j = 0; j < 3; ++j) {
        int p = tid * 3 + j;            // 0..767
        int m = p / 6, u = p - m * 6;
        int base = m * 25 + u * 4;
        float gi = bsl[u * 4 + 0], gf = bsl[u * 4 + 1], gg = bsl[u * 4 + 2], go = bsl[u * 4 + 3];
        #pragma unroll
        for (int w = 0; w < 4; ++w) {
          const float* q = gs + w * (BATCH * 25) + base;
          gi += q[0]; gf += q[1]; gg += q[2]; go += q[3];
        }
        float co = cb[u * BATCH + m];
        float cn = sigm(gf) * co + sigm(gi) * tanhf_(gg);
        float hn = sigm(go) * tanhf_(cn);
        cb[u * BATCH + m] = cn;
        hb[m * UPW + u] = f2bf(hn);
        if (layer) {
          out[((size_t)m * S_LEN + s) * HID + u0 + u] = hn;
          if (s == S_LEN - 1) {
            out[(size_t)BATCH * S_LEN * HID + (size_t)m * HID + u0 + u] = hn;                       // h1 final
            out[(size_t)BATCH * S_LEN * HID + (size_t)BATCH * HID + (size_t)m * HID + u0 + u] = cn; // c1 final
          }
        }
      }
      __syncthreads();
      // flush h slice (12B per batch row) to ring buffer
      for (int f = tid; f < BATCH * 3; f += 256) {
        int m = f / 3, q = f - m * 3;
        *((u32*)(hw + (size_t)m * HID + u0) + q) = ((const u32*)hb)[m * 3 + q];
      }
    }
    gbar(bar);
  }
}

extern "C" void kernel_launch(void* const* d_in, const int* in_sizes, int n_in,
                              void* d_out, int out_size, void* d_ws, size_t ws_size,
                              hipStream_t stream) {
  (void)in_sizes; (void)n_in; (void)out_size;
  if (ws_size < WS_NEED) return;   // need ~121 MB scratch

  const float* x      = (const float*)d_in[0];
  const float* h_init = (const float*)d_in[1];
  const float* c_init = (const float*)d_in[2];
  const float* Wih0 = (const float*)d_in[3];
  const float* Whh0 = (const float*)d_in[4];
  const float* bih0 = (const float*)d_in[5];
  const float* bhh0 = (const float*)d_in[6];
  const float* Wih1 = (const float*)d_in[7];
  const float* Whh1 = (const float*)d_in[8];
  const float* bih1 = (const float*)d_in[9];
  const float* bhh1 = (const float*)d_in[10];
  float* out = (float*)d_out;
  char* ws = (char*)d_ws;

  u16*   xbf = (u16*)(ws + XBF_OFF);
  u16*   W0p = (u16*)(ws + W0_OFF);
  u16*   W1p = (u16*)(ws + W1_OFF);
  float* b0p = (float*)(ws + B0_OFF);
  float* b1p = (float*)(ws + B1_OFF);
  u16*   r0  = (u16*)(ws + R0_OFF);
  u16*   r1  = (u16*)(ws + R1_OFF);
  u32*   bar = (u32*)(ws + BAR_OFF);

  hipMemsetAsync(bar, 0, 256, stream);
  prep_w<<<NCOLS, 256, 0, stream>>>(Wih0, Whh0, bih0, bhh0, Wih1, Whh1, bih1, bhh1, W0p, W1p, b0p, b1p);
  prep_x<<<2048, 256, 0, stream>>>(x, xbf);
  prep_state<<<(BATCH * HID + 255) / 256, 256, 0, stream>>>(h_init, r0, r1);

  hipFuncSetAttribute((const void*)lstm_persist, hipFuncAttributeMaxDynamicSharedMemorySize, DYN_LDS);

  const u16* xbf_c = xbf; const u16* W0_c = W0p; const u16* W1_c = W1p;
  const float* b0_c = b0p; const float* b1_c = b1p;
  void* params[] = {
    (void*)&xbf_c, (void*)&W0_c, (void*)&W1_c, (void*)&b0_c, (void*)&b1_c,
    (void*)&r0, (void*)&r1, (void*)&c_init, (void*)&out, (void*)&bar
  };
  hipLaunchCooperativeKernel((const void*)lstm_persist, dim3(NWG), dim3(256), params, DYN_LDS, stream);
}

// Round 2
// 11291.367 us; speedup vs baseline: 2.1373x; 2.1373x over previous
//
#include <hip/hip_runtime.h>
#include <hip/hip_bf16.h>

// LSTM decoder: 2 layers, B=128, S=512, I=H=768.
// Persistent cooperative kernel, layer-skewed pipeline, bf16 MFMA.
// R2: fence-free barrier (relaxed write-through atomics, tree arrival,
// single acquire-inv per tick), nt stores for out, deeper K unroll.

#define S_LEN 512
#define BATCH 128
#define HID   768
#define KDIM  1536          // I + H (concatenated GEMM K)
#define NCOLS 3072          // 4*H gate columns per layer
#define UPW   6             // hidden units per WG (768/128)
#define CPW   24            // gate cols per WG (4*UPW)
#define KSTR  1544          // LDS weight row stride in bf16 elems (1536 + 8 pad)
#define NWG   256

typedef unsigned short u16;
typedef unsigned int   u32;
typedef __attribute__((ext_vector_type(8))) __bf16 bf16x8;
typedef __attribute__((ext_vector_type(4))) float  f32x4;

// ---- ws layout (bytes) ----
static constexpr size_t XBF_OFF = 0;                                   // [S][B][I] bf16
static constexpr size_t XBF_BYTES = (size_t)S_LEN * BATCH * HID * 2;   // 100,663,296
static constexpr size_t W0_OFF  = XBF_OFF + XBF_BYTES;                 // [3072][1536] bf16 (permuted rows)
static constexpr size_t WP_BYTES = (size_t)NCOLS * KDIM * 2;           // 9,437,184
static constexpr size_t W1_OFF  = W0_OFF + WP_BYTES;
static constexpr size_t B0_OFF  = W1_OFF + WP_BYTES;                   // [3072] f32 (permuted, b_ih+b_hh)
static constexpr size_t B1_OFF  = B0_OFF + NCOLS * 4;
static constexpr size_t R0_OFF  = B1_OFF + NCOLS * 4;                  // [2][B][H] bf16 ring (layer0 h)
static constexpr size_t RING_BYTES = 2ull * BATCH * HID * 2;
static constexpr size_t R1_OFF  = R0_OFF + RING_BYTES;                 // [2][B][H] bf16 ring (layer1 h)
static constexpr size_t BAR_OFF = R1_OFF + RING_BYTES;                 // 8*128B cnt + 128B master + 128B flag
static constexpr size_t BAR_BYTES = 4096;
static constexpr size_t WS_NEED = BAR_OFF + BAR_BYTES;

// dynamic LDS layout (bytes)
static constexpr int WT_B  = 32 * KSTR * 2;          // 98,816 weight slice (24 real + 8 zero rows)
static constexpr int GS_B  = 4 * BATCH * 25 * 4;     // 51,200 per-wave partial gates [4][128][25]
static constexpr int CB_B  = UPW * BATCH * 4;        //  3,072 c-state [6][128]
static constexpr int BS_B  = 32 * 4;                 //    128 bias slice (24 used)
static constexpr int HB_B  = BATCH * UPW * 2;        //  1,536 h staging [128][6]
static constexpr int DYN_LDS = WT_B + GS_B + CB_B + BS_B + HB_B;   // 154,752 <= 160K

__device__ __forceinline__ u16 f2bf(float f) {
  u32 u = __float_as_uint(f);
  u = (u + 0x7fffu + ((u >> 16) & 1u)) >> 16;
  return (u16)u;
}
__device__ __forceinline__ float sigm(float x)  { return 1.0f / (1.0f + __expf(-x)); }
__device__ __forceinline__ float tanhf_(float x){ return 1.0f - 2.0f / (1.0f + __expf(2.0f * x)); }

// ---------- prep kernels ----------
__global__ void prep_w(const float* __restrict__ Wih0, const float* __restrict__ Whh0,
                       const float* __restrict__ bih0, const float* __restrict__ bhh0,
                       const float* __restrict__ Wih1, const float* __restrict__ Whh1,
                       const float* __restrict__ bih1, const float* __restrict__ bhh1,
                       u16* __restrict__ W0p, u16* __restrict__ W1p,
                       float* __restrict__ b0p, float* __restrict__ b1p) {
  int p = blockIdx.x;            // permuted row 0..3071:  p = u*4 + gate
  int u = p >> 2, g = p & 3;
  int n = g * HID + u;           // original gate row (i,f,g,o blocks of 768)
  const float* s0i = Wih0 + (size_t)n * HID;
  const float* s0h = Whh0 + (size_t)n * HID;
  const float* s1i = Wih1 + (size_t)n * HID;
  const float* s1h = Whh1 + (size_t)n * HID;
  u16* d0 = W0p + (size_t)p * KDIM;
  u16* d1 = W1p + (size_t)p * KDIM;
  for (int k = threadIdx.x; k < HID; k += blockDim.x) {
    d0[k]       = f2bf(s0i[k]);
    d0[k + HID] = f2bf(s0h[k]);
    d1[k]       = f2bf(s1i[k]);
    d1[k + HID] = f2bf(s1h[k]);
  }
  if (threadIdx.x == 0) { b0p[p] = bih0[n] + bhh0[n]; b1p[p] = bih1[n] + bhh1[n]; }
}

__global__ void prep_x(const float* __restrict__ x, u16* __restrict__ xbf) {
  // x [B][S][I] f32  ->  xbf [S][B][I] bf16
  const long long total4 = (long long)BATCH * S_LEN * HID / 4;
  long long stride = (long long)gridDim.x * blockDim.x;
  for (long long i4 = (long long)blockIdx.x * blockDim.x + threadIdx.x; i4 < total4; i4 += stride) {
    long long e = i4 * 4;
    int i = (int)(e % HID);
    long long bs = e / HID;
    int s = (int)(bs % S_LEN);
    int b = (int)(bs / S_LEN);
    float4 v = *(const float4*)(x + ((size_t)b * S_LEN + s) * HID + i);
    ushort4 o;
    o.x = f2bf(v.x); o.y = f2bf(v.y); o.z = f2bf(v.z); o.w = f2bf(v.w);
    *(ushort4*)(xbf + ((size_t)s * BATCH + b) * HID + i) = o;
  }
}

__global__ void prep_state(const float* __restrict__ h_init, u16* __restrict__ r0, u16* __restrict__ r1) {
  int i = blockIdx.x * blockDim.x + threadIdx.x;
  if (i < BATCH * HID) {
    u16 v = f2bf(h_init[i]);
    r0[BATCH * HID + i] = v;   // ring slot 1 = "step -1" state
    r1[BATCH * HID + i] = v;
  }
}

// ---------- fence-free grid barrier ----------
// Data handoff relies on: producers store h via relaxed agent-scope atomics
// (write-through to coherence point), then s_waitcnt 0 before relaxed arrival
// RMW. Consumers see flag flip via relaxed agent-scope (L2-bypassing) load,
// then issue ONE acquire fence (buffer_inv) to drop stale L1/L2 lines.
// Counters are monotonic across ticks -> no reset races.
__device__ __forceinline__ void gbar(u32* bar, int wg, int t) {
  __syncthreads();
  if (threadIdx.x == 0) {
    u32* cnt    = bar + (wg & 7) * 32;   // 8 group counters, 128B apart
    u32* master = bar + 8 * 32;          // own 128B line
    u32* flag   = bar + 9 * 32;          // own 128B line
    __builtin_amdgcn_s_waitcnt(0);       // all prior (write-through) stores complete
    u32 a = __hip_atomic_fetch_add(cnt, 1u, __ATOMIC_RELAXED, __HIP_MEMORY_SCOPE_AGENT);
    if (a == (u32)(32 * (t + 1) - 1)) {
      u32 b = __hip_atomic_fetch_add(master, 1u, __ATOMIC_RELAXED, __HIP_MEMORY_SCOPE_AGENT);
      if (b == (u32)(8 * (t + 1) - 1)) {
        __hip_atomic_store(flag, (u32)(t + 1), __ATOMIC_RELAXED, __HIP_MEMORY_SCOPE_AGENT);
      }
    }
    int spins = 0;
    while (__hip_atomic_load(flag, __ATOMIC_RELAXED, __HIP_MEMORY_SCOPE_AGENT) < (u32)(t + 1)) {
      __builtin_amdgcn_s_sleep(2);
      if ((++spins & 1023) == 0)
        __builtin_amdgcn_fence(__ATOMIC_ACQUIRE, "agent");  // deadlock safety net
    }
    __builtin_amdgcn_fence(__ATOMIC_ACQUIRE, "agent");      // one inv per tick
  }
  __syncthreads();
}

// ---------- persistent LSTM ----------
__global__ void __launch_bounds__(256, 1)
lstm_persist(const u16* __restrict__ xbf, const u16* __restrict__ W0p, const u16* __restrict__ W1p,
             const float* __restrict__ b0p, const float* __restrict__ b1p,
             u16* __restrict__ r0, u16* __restrict__ r1,
             const float* __restrict__ c_init, float* __restrict__ out, u32* bar)
{
  extern __shared__ char lds_raw[];
  u16*   wt  = (u16*)lds_raw;                       // [32][KSTR] bf16 weights (persistent)
  float* gs  = (float*)(lds_raw + WT_B);            // [4][128][25] per-wave partial gates
  float* cb  = (float*)(lds_raw + WT_B + GS_B);     // [6][128] c-state
  float* bsl = (float*)(lds_raw + WT_B + GS_B + CB_B); // [24] bias
  u16*   hb  = (u16*)(lds_raw + WT_B + GS_B + CB_B + BS_B); // [128][6] h staging

  const int wg    = blockIdx.x;
  const int layer = wg >> 7;        // 0..127 layer0, 128..255 layer1
  const int lw    = wg & 127;
  const int tid   = threadIdx.x;
  const int lane  = tid & 63;
  const int wv    = tid >> 6;       // wave 0..3, splits K into 4x384
  const int u0    = lw * UPW;       // global hidden-unit base
  const int p0    = lw * CPW;       // permuted weight-row base

  const u16* Wp  = layer ? W1p : W0p;
  const float* bp = layer ? b1p : b0p;

  // stage weight slice (rows 0..23 real, 24..31 zero) -- once, persists all steps
  for (int f = tid; f < 32 * (KSTR / 8); f += 256) {
    int r = f / (KSTR / 8), q = f - r * (KSTR / 8);
    uint4 v = make_uint4(0u, 0u, 0u, 0u);
    if (r < CPW && q < KDIM / 8) v = *(const uint4*)(Wp + (size_t)(p0 + r) * KDIM + q * 8);
    *(uint4*)(wt + r * KSTR + q * 8) = v;
  }
  if (tid < CPW) bsl[tid] = bp[p0 + tid];
  for (int f = tid; f < UPW * BATCH; f += 256) {
    int u = f >> 7, m = f & 127;
    cb[u * BATCH + m] = c_init[(size_t)m * HID + u0 + u];   // both layers init from c_init
  }
  __syncthreads();

  const int cA = lane & 15;             // MFMA n / C-col index
  const int kq = (lane >> 4) * 8;       // quad k offset within 32-chunk

  for (int tick = 0; tick <= S_LEN; ++tick) {
    const bool active = layer ? (tick >= 1) : (tick < S_LEN);
    if (active) {
      const int s = layer ? tick - 1 : tick;
      // A = [x_t | h0_prev] (layer0)  or  [h0_t | h1_prev] (layer1), rows=batch, bf16
      const u16* A0 = layer ? r0 + (size_t)(s & 1) * (BATCH * HID)
                            : xbf + (size_t)s * (BATCH * HID);
      const u16* A1 = layer ? r1 + (size_t)((s + 1) & 1) * (BATCH * HID)
                            : r0 + (size_t)((tick + 1) & 1) * (BATCH * HID);

      const u16* Ab = (wv & 2) ? A1 : A0;
      const u16* ap = Ab + (size_t)cA * HID + (wv & 1) * 384 + kq;
      const u16* wr = wt + (size_t)cA * KSTR + wv * 384 + kq;

      f32x4 acc[8][2];
      #pragma unroll
      for (int mt = 0; mt < 8; ++mt) { acc[mt][0] = (f32x4){0.f,0.f,0.f,0.f}; acc[mt][1] = (f32x4){0.f,0.f,0.f,0.f}; }

      #pragma unroll 6
      for (int kc = 0; kc < 12; ++kc) {
        bf16x8 b0 = *(const bf16x8*)(wr + kc * 32);
        bf16x8 b1 = *(const bf16x8*)(wr + kc * 32 + 16 * KSTR);
        #pragma unroll
        for (int mt = 0; mt < 8; ++mt) {
          bf16x8 a = *(const bf16x8*)(ap + kc * 32 + (size_t)mt * 16 * HID);
          acc[mt][0] = __builtin_amdgcn_mfma_f32_16x16x32_bf16(a, b0, acc[mt][0], 0, 0, 0);
          acc[mt][1] = __builtin_amdgcn_mfma_f32_16x16x32_bf16(a, b1, acc[mt][1], 0, 0, 0);
        }
      }

      // write per-wave partial gates to LDS  (C/D: col=lane&15, row=quad*4+reg)
      float* gsp = gs + wv * (BATCH * 25);
      const int rq = (lane >> 4) * 4;
      #pragma unroll
      for (int mt = 0; mt < 8; ++mt) {
        #pragma unroll
        for (int r = 0; r < 4; ++r) {
          gsp[(mt * 16 + rq + r) * 25 + cA] = acc[mt][0][r];
          if (cA < 8) gsp[(mt * 16 + rq + r) * 25 + 16 + cA] = acc[mt][1][r];
        }
      }
      __syncthreads();

      u16* hw = layer ? r1 + (size_t)(s & 1) * (BATCH * HID)
                      : r0 + (size_t)(tick & 1) * (BATCH * HID);

      // elementwise LSTM cell for this WG's 6 units x 128 batches
      #pragma unroll
      for (int j = 0; j < 3; ++j) {
        int p = tid * 3 + j;            // 0..767
        int m = p / 6, u = p - m * 6;
        int base = m * 25 + u * 4;
        float gi = bsl[u * 4 + 0], gf = bsl[u * 4 + 1], gg = bsl[u * 4 + 2], go = bsl[u * 4 + 3];
        #pragma unroll
        for (int w = 0; w < 4; ++w) {
          const float* q = gs + w * (BATCH * 25) + base;
          gi += q[0]; gf += q[1]; gg += q[2]; go += q[3];
        }
        float co = cb[u * BATCH + m];
        float cn = sigm(gf) * co + sigm(gi) * tanhf_(gg);
        float hn = sigm(go) * tanhf_(cn);
        cb[u * BATCH + m] = cn;
        hb[m * UPW + u] = f2bf(hn);
        if (layer) {
          __builtin_nontemporal_store(hn, &out[((size_t)m * S_LEN + s) * HID + u0 + u]);
          if (s == S_LEN - 1) {
            __builtin_nontemporal_store(hn, &out[(size_t)BATCH * S_LEN * HID + (size_t)m * HID + u0 + u]);                      // h1 final
            __builtin_nontemporal_store(cn, &out[(size_t)BATCH * S_LEN * HID + (size_t)BATCH * HID + (size_t)m * HID + u0 + u]); // c1 final
          }
        }
      }
      __syncthreads();
      // flush h slice (12B per batch row) to ring buffer -- relaxed agent-scope
      // atomic u32 stores = write-through to coherence point (no wbl2 needed)
      for (int f = tid; f < BATCH * 3; f += 256) {
        int m = f / 3, q = f - m * 3;
        __hip_atomic_store((u32*)(hw + (size_t)m * HID + u0) + q, ((const u32*)hb)[m * 3 + q],
                           __ATOMIC_RELAXED, __HIP_MEMORY_SCOPE_AGENT);
      }
    }
    gbar(bar, wg, tick);
  }
}

extern "C" void kernel_launch(void* const* d_in, const int* in_sizes, int n_in,
                              void* d_out, int out_size, void* d_ws, size_t ws_size,
                              hipStream_t stream) {
  (void)in_sizes; (void)n_in; (void)out_size;
  if (ws_size < WS_NEED) return;   // need ~121 MB scratch

  const float* x      = (const float*)d_in[0];
  const float* h_init = (const float*)d_in[1];
  const float* c_init = (const float*)d_in[2];
  const float* Wih0 = (const float*)d_in[3];
  const float* Whh0 = (const float*)d_in[4];
  const float* bih0 = (const float*)d_in[5];
  const float* bhh0 = (const float*)d_in[6];
  const float* Wih1 = (const float*)d_in[7];
  const float* Whh1 = (const float*)d_in[8];
  const float* bih1 = (const float*)d_in[9];
  const float* bhh1 = (const float*)d_in[10];
  float* out = (float*)d_out;
  char* ws = (char*)d_ws;

  u16*   xbf = (u16*)(ws + XBF_OFF);
  u16*   W0p = (u16*)(ws + W0_OFF);
  u16*   W1p = (u16*)(ws + W1_OFF);
  float* b0p = (float*)(ws + B0_OFF);
  float* b1p = (float*)(ws + B1_OFF);
  u16*   r0  = (u16*)(ws + R0_OFF);
  u16*   r1  = (u16*)(ws + R1_OFF);
  u32*   bar = (u32*)(ws + BAR_OFF);

  hipMemsetAsync(bar, 0, BAR_BYTES, stream);
  prep_w<<<NCOLS, 256, 0, stream>>>(Wih0, Whh0, bih0, bhh0, Wih1, Whh1, bih1, bhh1, W0p, W1p, b0p, b1p);
  prep_x<<<2048, 256, 0, stream>>>(x, xbf);
  prep_state<<<(BATCH * HID + 255) / 256, 256, 0, stream>>>(h_init, r0, r1);

  hipFuncSetAttribute((const void*)lstm_persist, hipFuncAttributeMaxDynamicSharedMemorySize, DYN_LDS);

  const u16* xbf_c = xbf; const u16* W0_c = W0p; const u16* W1_c = W1p;
  const float* b0_c = b0p; const float* b1_c = b1p;
  void* params[] = {
    (void*)&xbf_c, (void*)&W0_c, (void*)&W1_c, (void*)&b0_c, (void*)&b1_c,
    (void*)&r0, (void*)&r1, (void*)&c_init, (void*)&out, (void*)&bar
  };
  hipLaunchCooperativeKernel((const void*)lstm_persist, dim3(NWG), dim3(256), params, DYN_LDS, stream);
}